// Round 1
// baseline (96.684 us; speedup 1.0000x reference)
//
#include <hip/hip_runtime.h>
#include <math.h>

// Problem constants (fixed by setup_inputs)
#define NB 16
#define NA 5
#define NC 20
#define NH 64
#define NW 64
#define MAXGT 50
#define NGT (NB * MAXGT)          // 800
#define CELLS (NH * NW)           // 4096
#define CH (NA * (5 + NC))        // 125
#define TOTAL (NB * NA * NH * NW) // 327680
#define SIL_THRESH 0.6f
#define OBJECT_SCALE 5.0f

__device__ __forceinline__ float sigmoidf_(float v) {
    return 1.0f / (1.0f + __expf(-v));
}

// -------- Kernel A: per-GT precompute (800 GTs) + zero d_out --------
__global__ __launch_bounds__(256) void gt_prep(
    const float* __restrict__ out, const float* __restrict__ tgt,
    const float* __restrict__ anc, float* __restrict__ ws_f,
    int* __restrict__ ws_i, float* __restrict__ d_out)
{
    int g = blockIdx.x * blockDim.x + threadIdx.x;
    if (g == 0) d_out[0] = 0.0f;   // runs before kernel B (stream order)
    if (g >= NGT) return;

    int b = g / MAXGT;
    const float* t = tgt + (size_t)g * 5;
    float cls = t[0], xn = t[1], yn = t[2], wn = t[3], hn = t[4];
    bool valid = xn > 0.0f;
    float gx = xn * NW, gy = yn * NH, gw = wn * NW, gh = hn * NH;

    // best anchor: IoU of (0,0,gw,gh) vs (0,0,aw,ah) = min*min / union; first max wins
    int bn = 0; float best = -1.0f;
    for (int a = 0; a < NA; ++a) {
        float aw = anc[2 * a], ah = anc[2 * a + 1];
        float inter = fminf(aw, gw) * fminf(ah, gh);
        float uni = aw * ah + gw * gh - inter;
        float iou = uni > 0.0f ? inter / uni : 0.0f;
        if (iou > best) { best = iou; bn = a; }
    }
    float aw = anc[2 * bn], ah = anc[2 * bn + 1];
    int gi = (int)gx; gi = gi < 0 ? 0 : (gi > NW - 1 ? NW - 1 : gi);
    int gj = (int)gy; gj = gj < 0 ? 0 : (gj > NH - 1 ? NH - 1 : gj);
    int flat = ((b * NA + bn) * NH + gj) * NW + gi;

    // pred box at the scatter cell
    int cell = gj * NW + gi;
    const float* base = out + ((size_t)b * CH + bn * 25) * CELLS + cell;
    float xr = base[0];
    float yr = base[CELLS];
    float wr = base[2 * CELLS];
    float hr = base[3 * CELLS];
    float px = sigmoidf_(xr) + (float)gi;
    float py = sigmoidf_(yr) + (float)gj;
    float pw = __expf(wr) * aw;
    float ph = __expf(hr) * ah;

    // IoU(pred, gt)
    float ax1 = px - pw * 0.5f, ax2 = px + pw * 0.5f;
    float ay1 = py - ph * 0.5f, ay2 = py + ph * 0.5f;
    float bx1 = gx - gw * 0.5f, bx2 = gx + gw * 0.5f;
    float by1 = gy - gh * 0.5f, by2 = gy + gh * 0.5f;
    float iw = fmaxf(fminf(ax2, bx2) - fmaxf(ax1, bx1), 0.0f);
    float ih = fmaxf(fminf(ay2, by2) - fmaxf(ay1, by1), 0.0f);
    float inter = iw * ih;
    float uni = pw * ph + gw * gh - inter;
    float iou = uni > 0.0f ? inter / uni : 0.0f;

    // SoA into workspace
    ws_f[0 * NGT + g] = bx1;
    ws_f[1 * NGT + g] = bx2;
    ws_f[2 * NGT + g] = by1;
    ws_f[3 * NGT + g] = by2;
    ws_f[4 * NGT + g] = gw * gh;
    ws_f[5 * NGT + g] = gx - (float)gi;                       // tx
    ws_f[6 * NGT + g] = gy - (float)gj;                       // ty
    ws_f[7 * NGT + g] = __logf(fmaxf(gw, 1e-12f) / aw);       // tw
    ws_f[8 * NGT + g] = __logf(fmaxf(gh, 1e-12f) / ah);       // th
    ws_f[9 * NGT + g] = iou;                                  // tconf
    ws_i[0 * NGT + g] = valid ? flat : -1;
    ws_i[1 * NGT + g] = (int)cls;
}

// -------- Kernel B: per-cell loss + reduction --------
__global__ __launch_bounds__(256) void yolo_loss(
    const float* __restrict__ out, const float* __restrict__ anc,
    const float* __restrict__ ws_f, const int* __restrict__ ws_i,
    float* __restrict__ d_out)
{
    __shared__ float s_bx1[MAXGT], s_bx2[MAXGT], s_by1[MAXGT], s_by2[MAXGT];
    __shared__ float s_area[MAXGT], s_tx[MAXGT], s_ty[MAXGT], s_tw[MAXGT];
    __shared__ float s_th[MAXGT], s_tc[MAXGT];
    __shared__ int s_flat[MAXGT], s_cls[MAXGT];

    int idx = blockIdx.x * 256 + threadIdx.x;   // global cell id in [0, TOTAL)
    int b = idx / (NA * CELLS);                 // block-uniform (20480 % 256 == 0)

    if (threadIdx.x < MAXGT) {
        int g = b * MAXGT + threadIdx.x;
        s_bx1[threadIdx.x]  = ws_f[0 * NGT + g];
        s_bx2[threadIdx.x]  = ws_f[1 * NGT + g];
        s_by1[threadIdx.x]  = ws_f[2 * NGT + g];
        s_by2[threadIdx.x]  = ws_f[3 * NGT + g];
        s_area[threadIdx.x] = ws_f[4 * NGT + g];
        s_tx[threadIdx.x]   = ws_f[5 * NGT + g];
        s_ty[threadIdx.x]   = ws_f[6 * NGT + g];
        s_tw[threadIdx.x]   = ws_f[7 * NGT + g];
        s_th[threadIdx.x]   = ws_f[8 * NGT + g];
        s_tc[threadIdx.x]   = ws_f[9 * NGT + g];
        s_flat[threadIdx.x] = ws_i[0 * NGT + g];
        s_cls[threadIdx.x]  = ws_i[1 * NGT + g];
    }
    __syncthreads();

    int r = idx - b * NA * CELLS;
    int a = r / CELLS;
    int cell = r - a * CELLS;
    int j = cell / NW, i = cell - j * NW;

    const float* base = out + ((size_t)b * CH + a * 25) * CELLS + cell;
    float xr = base[0];
    float yr = base[CELLS];
    float wr = base[2 * CELLS];
    float hr = base[3 * CELLS];
    float cr = base[4 * CELLS];

    float sx = sigmoidf_(xr), sy = sigmoidf_(yr), sc = sigmoidf_(cr);
    float aw = anc[2 * a], ah = anc[2 * a + 1];
    float pw = __expf(wr) * aw, ph = __expf(hr) * ah;
    float px = sx + (float)i, py = sy + (float)j;
    float ax1 = px - pw * 0.5f, ax2 = px + pw * 0.5f;
    float ay1 = py - ph * 0.5f, ay2 = py + ph * 0.5f;
    float parea = pw * ph;

    float maxiou = 0.0f;
    int match = -1;  // last-wins to mirror sequential scatter semantics
    #pragma unroll 10
    for (int g = 0; g < MAXGT; ++g) {
        int fg = s_flat[g];
        if (fg < 0) continue;
        float iw = fmaxf(fminf(ax2, s_bx2[g]) - fmaxf(ax1, s_bx1[g]), 0.0f);
        float ih = fmaxf(fminf(ay2, s_by2[g]) - fmaxf(ay1, s_by1[g]), 0.0f);
        float inter = iw * ih;
        float uni = parea + s_area[g] - inter;
        float iou = uni > 0.0f ? inter / uni : 0.0f;
        maxiou = fmaxf(maxiou, iou);
        if (fg == idx) match = g;
    }

    float tx = 0.5f, ty = 0.5f, tw = 0.0f, th = 0.0f, tconf = 0.0f;
    float cscale = (maxiou > SIL_THRESH) ? 0.0f : 1.0f;
    float loss = 0.0f;

    if (match >= 0) {
        tx = s_tx[match]; ty = s_ty[match];
        tw = s_tw[match]; th = s_th[match];
        tconf = s_tc[match]; cscale = OBJECT_SCALE;
        // class NLL via stable log-softmax over 20 logits
        const float* cl = base + 5 * CELLS;
        float lg[NC];
        float mx = -1e30f;
        #pragma unroll
        for (int c = 0; c < NC; ++c) { lg[c] = cl[c * CELLS]; mx = fmaxf(mx, lg[c]); }
        float se = 0.0f;
        #pragma unroll
        for (int c = 0; c < NC; ++c) se += __expf(lg[c] - mx);
        float lse = mx + __logf(se);
        loss += lse - lg[s_cls[match]];
    }

    float dx = sx - tx, dy = sy - ty, dw = wr - tw, dh = hr - th, dc = sc - tconf;
    loss += 0.5f * (dx * dx + dy * dy + dw * dw + dh * dh)
          + 0.5f * cscale * dc * dc;

    // wave-64 shuffle reduce, then cross-wave LDS reduce, one atomic per block
    float v = loss;
    #pragma unroll
    for (int off = 32; off > 0; off >>= 1) v += __shfl_down(v, off, 64);
    __shared__ float ssum[4];
    int lane = threadIdx.x & 63, wv = threadIdx.x >> 6;
    if (lane == 0) ssum[wv] = v;
    __syncthreads();
    if (threadIdx.x == 0)
        atomicAdd(d_out, ssum[0] + ssum[1] + ssum[2] + ssum[3]);
}

extern "C" void kernel_launch(void* const* d_in, const int* in_sizes, int n_in,
                              void* d_out, int out_size, void* d_ws, size_t ws_size,
                              hipStream_t stream) {
    const float* out = (const float*)d_in[0];
    const float* tgt = (const float*)d_in[1];
    const float* anc = (const float*)d_in[2];
    float* ws_f = (float*)d_ws;
    int*   ws_i = (int*)((char*)d_ws + (size_t)10 * NGT * sizeof(float));
    float* o = (float*)d_out;

    gt_prep<<<(NGT + 255) / 256, 256, 0, stream>>>(out, tgt, anc, ws_f, ws_i, o);
    yolo_loss<<<TOTAL / 256, 256, 0, stream>>>(out, anc, ws_f, ws_i, o);
}

// Round 2
// 88.609 us; speedup vs baseline: 1.0911x; 1.0911x over previous
//
#include <hip/hip_runtime.h>
#include <math.h>

// Problem constants (fixed by setup_inputs)
#define NB 16
#define NA 5
#define NC 20
#define NH 64
#define NW 64
#define MAXGT 50
#define NGT (NB * MAXGT)          // 800
#define CELLS (NH * NW)           // 4096
#define CH (NA * (5 + NC))        // 125
#define TOTAL (NB * NA * NH * NW) // 327680
#define OBJECT_SCALE 5.0f

// ws layout (bytes from d_ws base):
//   ws_box  : float4[NGT]          @ 0        (12800 B)  {bx1,bx2,by1,by2}
//   ws_epi  : float4[2*NGT]        @ 12800    (25600 B)  {tx,ty,tw,th},{tconf,cls,0,0}
//   ws_thr  : float [NGT]          @ 38400    ( 3200 B)  0.375*area (huge if invalid)
//   ws_flat : int   [NGT]          @ 41600    ( 3200 B)  scatter cell id, -1 if invalid
#define WS_BOX_OFF  0
#define WS_EPI_OFF  12800
#define WS_THR_OFF  38400
#define WS_FLAT_OFF 41600

__device__ __forceinline__ float fast_sigmoid(float v) {
    return __builtin_amdgcn_rcpf(1.0f + __expf(-v));
}

// -------- Kernel A: per-GT precompute (800 GTs) + zero d_out --------
__global__ __launch_bounds__(256) void gt_prep(
    const float* __restrict__ out, const float* __restrict__ tgt,
    const float* __restrict__ anc, float4* __restrict__ ws_box,
    float4* __restrict__ ws_epi, float* __restrict__ ws_thr,
    int* __restrict__ ws_flat, float* __restrict__ d_out)
{
    int g = blockIdx.x * blockDim.x + threadIdx.x;
    if (g == 0) d_out[0] = 0.0f;   // stream order: runs before yolo_loss
    if (g >= NGT) return;

    int b = g / MAXGT;
    const float* t = tgt + (size_t)g * 5;
    float cls = t[0], xn = t[1], yn = t[2], wn = t[3], hn = t[4];
    bool valid = xn > 0.0f;
    float gx = xn * NW, gy = yn * NH, gw = wn * NW, gh = hn * NH;

    // best anchor (first max wins)
    int bn = 0; float best = -1.0f;
    for (int a = 0; a < NA; ++a) {
        float aw = anc[2 * a], ah = anc[2 * a + 1];
        float inter = fminf(aw, gw) * fminf(ah, gh);
        float uni = aw * ah + gw * gh - inter;
        float iou = uni > 0.0f ? inter / uni : 0.0f;
        if (iou > best) { best = iou; bn = a; }
    }
    float aw = anc[2 * bn], ah = anc[2 * bn + 1];
    int gi = (int)gx; gi = gi < 0 ? 0 : (gi > NW - 1 ? NW - 1 : gi);
    int gj = (int)gy; gj = gj < 0 ? 0 : (gj > NH - 1 ? NH - 1 : gj);
    int flat = ((b * NA + bn) * NH + gj) * NW + gi;

    // pred box at scatter cell -> tconf = IoU(pred, gt)
    int cell = gj * NW + gi;
    const float* base = out + ((size_t)b * CH + bn * 25) * CELLS + cell;
    float xr = base[0];
    float yr = base[CELLS];
    float wr = base[2 * CELLS];
    float hr = base[3 * CELLS];
    float px = fast_sigmoid(xr) + (float)gi;
    float py = fast_sigmoid(yr) + (float)gj;
    float pw = __expf(wr) * aw;
    float ph = __expf(hr) * ah;

    float bx1 = gx - gw * 0.5f, bx2 = gx + gw * 0.5f;
    float by1 = gy - gh * 0.5f, by2 = gy + gh * 0.5f;
    float ax1 = px - pw * 0.5f, ax2 = px + pw * 0.5f;
    float ay1 = py - ph * 0.5f, ay2 = py + ph * 0.5f;
    float iw = fmaxf(fminf(ax2, bx2) - fmaxf(ax1, bx1), 0.0f);
    float ih = fmaxf(fminf(ay2, by2) - fmaxf(ay1, by1), 0.0f);
    float inter = iw * ih;
    float uni = pw * ph + gw * gh - inter;
    float iou = uni > 0.0f ? inter / uni : 0.0f;

    if (valid) {
        ws_box[g] = make_float4(bx1, bx2, by1, by2);
        ws_thr[g] = 0.375f * (gw * gh);   // inner-loop test: inter > 0.375*parea + thr
        ws_flat[g] = flat;
    } else {
        // empty box: iw,ih clamp to 0; threshold unreachable; flat never matches
        ws_box[g] = make_float4(3e18f, -3e18f, 3e18f, -3e18f);
        ws_thr[g] = 3e18f;
        ws_flat[g] = -1;
    }
    ws_epi[2 * g]     = make_float4(gx - (float)gi, gy - (float)gj,
                                    __logf(fmaxf(gw, 1e-12f) / aw),
                                    __logf(fmaxf(gh, 1e-12f) / ah));
    ws_epi[2 * g + 1] = make_float4(iou, cls, 0.0f, 0.0f);
}

// -------- Kernel B: per-cell loss (2 cells/thread) + reduction --------
__global__ __launch_bounds__(256) void yolo_loss(
    const float* __restrict__ out, const float* __restrict__ anc,
    const float4* __restrict__ ws_box, const float4* __restrict__ ws_epi,
    const float* __restrict__ ws_thr, const int* __restrict__ ws_flat,
    float* __restrict__ d_out)
{
    __shared__ float4 s_box[MAXGT];
    __shared__ float  s_thr[MAXGT];
    __shared__ int    s_flat[MAXGT];
    __shared__ float  ssum[4];

    int tid = threadIdx.x;
    int b = blockIdx.x / 40;                 // 40 blocks per batch (uniform)

    if (tid < MAXGT) {
        int g = b * MAXGT + tid;
        s_box[tid]  = ws_box[g];
        s_thr[tid]  = ws_thr[g];
        s_flat[tid] = ws_flat[g];
    }
    __syncthreads();

    int q = blockIdx.x * 256 + tid;
    int id0 = 2 * q;                         // this thread's two global cell ids
    int r = id0 - b * (NA * CELLS);
    int a = r >> 12;                         // /CELLS (uniform per block)
    int cell = r & (CELLS - 1);
    int j = cell >> 6, i = cell & 63;        // i is even; cells (i, i+1) same row

    const float* base = out + (((size_t)(b * CH + a * 25)) << 12) + cell;
    float2 xr = *(const float2*)(base);
    float2 yr = *(const float2*)(base + CELLS);
    float2 wr = *(const float2*)(base + 2 * CELLS);
    float2 hr = *(const float2*)(base + 3 * CELLS);
    float2 cr = *(const float2*)(base + 4 * CELLS);

    float aw = anc[2 * a], ah = anc[2 * a + 1];

    // per-cell predicted boxes
    float sx0 = fast_sigmoid(xr.x), sx1 = fast_sigmoid(xr.y);
    float sy0 = fast_sigmoid(yr.x), sy1 = fast_sigmoid(yr.y);
    float pw0 = __expf(wr.x) * aw,  pw1 = __expf(wr.y) * aw;
    float ph0 = __expf(hr.x) * ah,  ph1 = __expf(hr.y) * ah;
    float px0 = sx0 + (float)i,     px1 = sx1 + (float)(i + 1);
    float py0 = sy0 + (float)j,     py1 = sy1 + (float)j;

    float ax1_0 = px0 - pw0 * 0.5f, ax2_0 = px0 + pw0 * 0.5f;
    float ay1_0 = py0 - ph0 * 0.5f, ay2_0 = py0 + ph0 * 0.5f;
    float ax1_1 = px1 - pw1 * 0.5f, ax2_1 = px1 + pw1 * 0.5f;
    float ay1_1 = py1 - ph1 * 0.5f, ay2_1 = py1 + ph1 * 0.5f;
    float pthr0 = 0.375f * (pw0 * ph0);
    float pthr1 = 0.375f * (pw1 * ph1);

    float sil0 = -1.0f, sil1 = -1.0f;
    int m0 = -1, m1 = -1;

    #pragma unroll 10
    for (int g = 0; g < MAXGT; ++g) {
        float4 B = s_box[g];
        float tg = s_thr[g];
        int fg = s_flat[g];

        float iw0 = fminf(ax2_0, B.y) - fmaxf(ax1_0, B.x);
        float ih0 = fminf(ay2_0, B.w) - fmaxf(ay1_0, B.z);
        float in0 = fmaxf(iw0, 0.0f) * fmaxf(ih0, 0.0f);
        sil0 = fmaxf(sil0, in0 - (pthr0 + tg));

        float iw1 = fminf(ax2_1, B.y) - fmaxf(ax1_1, B.x);
        float ih1 = fminf(ay2_1, B.w) - fmaxf(ay1_1, B.z);
        float in1 = fmaxf(iw1, 0.0f) * fmaxf(ih1, 0.0f);
        sil1 = fmaxf(sil1, in1 - (pthr1 + tg));

        m0 = (fg == id0)     ? g : m0;   // last-wins scatter semantics
        m1 = (fg == id0 + 1) ? g : m1;
    }

    float sc0 = fast_sigmoid(cr.x), sc1 = fast_sigmoid(cr.y);
    float loss = 0.0f;

    // --- cell 0 epilogue ---
    {
        float tx = 0.5f, ty = 0.5f, tw = 0.0f, th = 0.0f, tc = 0.0f;
        float cs = (sil0 > 0.0f) ? 0.0f : 1.0f;
        if (m0 >= 0) {
            int g = b * MAXGT + m0;
            float4 e0 = ws_epi[2 * g], e1 = ws_epi[2 * g + 1];
            tx = e0.x; ty = e0.y; tw = e0.z; th = e0.w;
            tc = e1.x; cs = OBJECT_SCALE;
            int cls = (int)e1.y;
            const float* cl = base + 5 * CELLS;           // cell 0 class logits
            float mx = -1e30f;
            #pragma unroll
            for (int c = 0; c < NC; ++c) mx = fmaxf(mx, cl[c * CELLS]);
            float se = 0.0f, lt = 0.0f;
            #pragma unroll
            for (int c = 0; c < NC; ++c) {
                float v = cl[c * CELLS];
                se += __expf(v - mx);
                if (c == cls) lt = v;
            }
            loss += mx + __logf(se) - lt;
        }
        float dx = sx0 - tx, dy = sy0 - ty, dw = wr.x - tw, dh = hr.x - th, dc = sc0 - tc;
        loss += 0.5f * (dx * dx + dy * dy + dw * dw + dh * dh) + 0.5f * cs * dc * dc;
    }
    // --- cell 1 epilogue ---
    {
        float tx = 0.5f, ty = 0.5f, tw = 0.0f, th = 0.0f, tc = 0.0f;
        float cs = (sil1 > 0.0f) ? 0.0f : 1.0f;
        if (m1 >= 0) {
            int g = b * MAXGT + m1;
            float4 e0 = ws_epi[2 * g], e1 = ws_epi[2 * g + 1];
            tx = e0.x; ty = e0.y; tw = e0.z; th = e0.w;
            tc = e1.x; cs = OBJECT_SCALE;
            int cls = (int)e1.y;
            const float* cl = base + 1 + 5 * CELLS;       // cell 1 class logits
            float mx = -1e30f;
            #pragma unroll
            for (int c = 0; c < NC; ++c) mx = fmaxf(mx, cl[c * CELLS]);
            float se = 0.0f, lt = 0.0f;
            #pragma unroll
            for (int c = 0; c < NC; ++c) {
                float v = cl[c * CELLS];
                se += __expf(v - mx);
                if (c == cls) lt = v;
            }
            loss += mx + __logf(se) - lt;
        }
        float dx = sx1 - tx, dy = sy1 - ty, dw = wr.y - tw, dh = hr.y - th, dc = sc1 - tc;
        loss += 0.5f * (dx * dx + dy * dy + dw * dw + dh * dh) + 0.5f * cs * dc * dc;
    }

    // wave-64 shuffle reduce -> cross-wave LDS -> one atomic per block
    float v = loss;
    #pragma unroll
    for (int off = 32; off > 0; off >>= 1) v += __shfl_down(v, off, 64);
    int lane = tid & 63, wv = tid >> 6;
    if (lane == 0) ssum[wv] = v;
    __syncthreads();
    if (tid == 0)
        atomicAdd(d_out, ssum[0] + ssum[1] + ssum[2] + ssum[3]);
}

extern "C" void kernel_launch(void* const* d_in, const int* in_sizes, int n_in,
                              void* d_out, int out_size, void* d_ws, size_t ws_size,
                              hipStream_t stream) {
    const float* out = (const float*)d_in[0];
    const float* tgt = (const float*)d_in[1];
    const float* anc = (const float*)d_in[2];
    char* ws = (char*)d_ws;
    float4* ws_box = (float4*)(ws + WS_BOX_OFF);
    float4* ws_epi = (float4*)(ws + WS_EPI_OFF);
    float* ws_thr = (float*)(ws + WS_THR_OFF);
    int* ws_flat = (int*)(ws + WS_FLAT_OFF);
    float* o = (float*)d_out;

    gt_prep<<<(NGT + 255) / 256, 256, 0, stream>>>(out, tgt, anc, ws_box, ws_epi,
                                                   ws_thr, ws_flat, o);
    yolo_loss<<<(TOTAL / 2) / 256, 256, 0, stream>>>(out, anc, ws_box, ws_epi,
                                                     ws_thr, ws_flat, o);
}